// Round 7
// baseline (1078.065 us; speedup 1.0000x reference)
//
#include <hip/hip_runtime.h>
#include <hip/hip_bf16.h>

typedef __attribute__((ext_vector_type(8))) short short8;
typedef __attribute__((ext_vector_type(4))) float f32x4;
typedef __attribute__((ext_vector_type(16))) float f32x16;
typedef unsigned short ushort_t;

static constexpr int Bc = 2, Sc = 2048, HIDc = 4096, Hc = 32;
static constexpr int NOPEc = 128, ROPEc = 64, VDc = 128, QHDc = 192;
static constexpr int QLRc = 1536, KVLRc = 512;

#define CDIV(a,b) (((a)+(b)-1)/(b))

__device__ __forceinline__ float bf2f(ushort_t u){
  union { unsigned u32; float f; } x; x.u32 = ((unsigned)u) << 16; return x.f;
}
__device__ __forceinline__ ushort_t f2bf(float f){
  union { float f; unsigned u32; } x; x.f = f;
  unsigned r = x.u32 + 0x7FFFu + ((x.u32 >> 16) & 1u);
  return (ushort_t)(r >> 16);
}
__device__ __forceinline__ void gload16(const void* g, void* l){
  __builtin_amdgcn_global_load_lds((const __attribute__((address_space(1))) void*)g,
                                   (__attribute__((address_space(3))) void*)l, 16, 0, 0);
}

// ---------------- f32 -> bf16 convert (vectorized, grid-stride) ----------------
__global__ __launch_bounds__(256)
void f32_to_bf16(const float* __restrict__ in, ushort_t* __restrict__ out, long long n){
  long long stride = (long long)gridDim.x * 256 * 4;
  for (long long i = ((long long)blockIdx.x*256 + threadIdx.x)*4; i < n; i += stride){
    float4 v = *(const float4*)(in + i);
    unsigned long long pk = (unsigned long long)f2bf(v.x)
                          | ((unsigned long long)f2bf(v.y) << 16)
                          | ((unsigned long long)f2bf(v.z) << 32)
                          | ((unsigned long long)f2bf(v.w) << 48);
    *(unsigned long long*)(out + i) = pk;
  }
}

// ---------------- batched 5-segment f32->bf16 (hidden + 4 weights) ----------------
__global__ __launch_bounds__(256)
void conv_all(const float* __restrict__ s0, const float* __restrict__ s1,
              const float* __restrict__ s2, const float* __restrict__ s3,
              const float* __restrict__ s4,
              ushort_t* __restrict__ d0, ushort_t* __restrict__ d1,
              ushort_t* __restrict__ d2, ushort_t* __restrict__ d3,
              ushort_t* __restrict__ d4){
  constexpr long long C0 = 16777216, C1 = 23068672, C2 = 32505856, C3 = 34865152, C4 = 39059456;
  long long stride = (long long)gridDim.x * 256 * 4;
  for (long long e = ((long long)blockIdx.x*256 + threadIdx.x)*4; e < C4; e += stride){
    const float* sp; ushort_t* dp; long long o;
    if      (e < C0){ sp = s0; dp = d0; o = e; }
    else if (e < C1){ sp = s1; dp = d1; o = e - C0; }
    else if (e < C2){ sp = s2; dp = d2; o = e - C1; }
    else if (e < C3){ sp = s3; dp = d3; o = e - C2; }
    else            { sp = s4; dp = d4; o = e - C3; }
    float4 v = *(const float4*)(sp + o);
    unsigned long long pk = (unsigned long long)f2bf(v.x)
                          | ((unsigned long long)f2bf(v.y) << 16)
                          | ((unsigned long long)f2bf(v.z) << 32)
                          | ((unsigned long long)f2bf(v.w) << 48);
    *(unsigned long long*)(dp + o) = pk;
  }
}

// ======== GEMM 256x256 tile, BK=64, 8 waves, dbuf LDS, swizzled, counted vmcnt ======
template<bool OUTBF>
__global__ __launch_bounds__(512, 2)
void gemm256(const ushort_t* __restrict__ A, const ushort_t* __restrict__ Bw,
             void* __restrict__ Cp, int M, int N, int K, int lda)
{
  __shared__ __attribute__((aligned(16))) ushort_t sm[65536];
  const int tid = threadIdx.x, lane = tid & 63, w = tid >> 6;
  const int wr = w >> 2, wc = w & 3;
  const int fr = lane & 15, kq = lane >> 4;

  const int nwg = gridDim.x, nx = N >> 8;
  const int bid = blockIdx.x;
  const int swz = (bid & 7) * (nwg >> 3) + (bid >> 3);
  const int m0 = (swz / nx) << 8, n0 = (swz % nx) << 8;

  f32x4 acc[8][4];
  #pragma unroll
  for (int m=0;m<8;m++)
    #pragma unroll
    for (int n=0;n<4;n++) acc[m][n] = (f32x4){0.f,0.f,0.f,0.f};

  const int srow = tid >> 3;
  const int gch  = (tid & 7) ^ (srow & 7);

  auto stage = [&](int c, int kt){
    const int k0 = kt << 6;
    ushort_t* Al = sm + c*16384;
    ushort_t* Bl = sm + 32768 + c*16384;
    const ushort_t* Ag = A  + (size_t)(m0 + srow)*lda + k0 + gch*8;
    const ushort_t* Bg = Bw + (size_t)(n0 + srow)*K   + k0 + gch*8;
    #pragma unroll
    for (int i=0;i<4;i++) gload16(Ag + (size_t)(i*64)*lda, Al + i*4096 + tid*8);
    #pragma unroll
    for (int i=0;i<4;i++) gload16(Bg + (size_t)(i*64)*K,   Bl + i*4096 + tid*8);
  };

  auto compute = [&](int c){
    const ushort_t* Al = sm + c*16384;
    const ushort_t* Bl = sm + 32768 + c*16384;
    const int s = fr & 7;
    short8 bfr[4][2];
    #pragma unroll
    for (int n=0;n<4;n++){
      const int row = wc*64 + n*16 + fr;
      bfr[n][0] = *(const short8*)(Bl + row*64 + ((kq    ) ^ s)*8);
      bfr[n][1] = *(const short8*)(Bl + row*64 + ((kq + 4) ^ s)*8);
    }
    #pragma unroll
    for (int m=0;m<8;m++){
      const int row = wr*128 + m*16 + fr;
      short8 a0 = *(const short8*)(Al + row*64 + ((kq    ) ^ s)*8);
      short8 a1 = *(const short8*)(Al + row*64 + ((kq + 4) ^ s)*8);
      #pragma unroll
      for (int n=0;n<4;n++){
        acc[m][n] = __builtin_amdgcn_mfma_f32_16x16x32_bf16(a0, bfr[n][0], acc[m][n], 0,0,0);
        acc[m][n] = __builtin_amdgcn_mfma_f32_16x16x32_bf16(a1, bfr[n][1], acc[m][n], 0,0,0);
      }
    }
  };

  const int nkt = K >> 6;
  stage(0, 0);
  stage(1, 1);
  asm volatile("s_waitcnt vmcnt(8)" ::: "memory");
  __builtin_amdgcn_s_barrier();
  __builtin_amdgcn_sched_barrier(0);

  int cur = 0;
  for (int kt = 0; kt < nkt; ++kt){
    compute(cur);
    __builtin_amdgcn_s_barrier();
    __builtin_amdgcn_sched_barrier(0);
    if (kt + 2 < nkt){
      stage(cur, kt + 2);
      asm volatile("s_waitcnt vmcnt(8)" ::: "memory");
    } else {
      asm volatile("s_waitcnt vmcnt(0)" ::: "memory");
    }
    __builtin_amdgcn_s_barrier();
    __builtin_amdgcn_sched_barrier(0);
    cur ^= 1;
  }

  const int rb = m0 + wr*128 + kq*4;
  const int cb = n0 + wc*64 + fr;
  #pragma unroll
  for (int m=0;m<8;m++)
    #pragma unroll
    for (int n=0;n<4;n++){
      const int col = cb + n*16;
      #pragma unroll
      for (int j=0;j<4;j++){
        const int row = rb + m*16 + j;
        float v = acc[m][n][j];
        if (OUTBF) ((ushort_t*)Cp)[(size_t)row*N + col] = f2bf(v);
        else       ((float*)  Cp)[(size_t)row*N + col] = v;
      }
    }
}

// ======== GEMM 256x128 tile, BK=64, 8 waves (4Mx2N), dbuf, counted vmcnt ======
template<bool OUTBF>
__global__ __launch_bounds__(512, 2)
void gemm256x128(const ushort_t* __restrict__ A, const ushort_t* __restrict__ Bw,
                 void* __restrict__ Cp, int M, int N, int K, int lda)
{
  __shared__ __attribute__((aligned(16))) ushort_t sm[49152];
  const int tid = threadIdx.x, lane = tid & 63, w = tid >> 6;
  const int wr = w >> 1, wc = w & 1;
  const int fr = lane & 15, kq = lane >> 4;

  const int nwg = gridDim.x, nx = N >> 7;
  const int bid = blockIdx.x;
  const int swz = (bid & 7) * (nwg >> 3) + (bid >> 3);
  const int m0 = (swz / nx) << 8, n0 = (swz % nx) << 7;

  f32x4 acc[4][4];
  #pragma unroll
  for (int m=0;m<4;m++)
    #pragma unroll
    for (int n=0;n<4;n++) acc[m][n] = (f32x4){0.f,0.f,0.f,0.f};

  const int srow = tid >> 3;
  const int gch  = (tid & 7) ^ (srow & 7);

  auto stage = [&](int c, int kt){
    const int k0 = kt << 6;
    ushort_t* Al = sm + c*16384;
    ushort_t* Bl = sm + 32768 + c*8192;
    const ushort_t* Ag = A  + (size_t)(m0 + srow)*lda + k0 + gch*8;
    const ushort_t* Bg = Bw + (size_t)(n0 + srow)*K   + k0 + gch*8;
    #pragma unroll
    for (int i=0;i<4;i++) gload16(Ag + (size_t)(i*64)*lda, Al + i*4096 + tid*8);
    #pragma unroll
    for (int i=0;i<2;i++) gload16(Bg + (size_t)(i*64)*K,   Bl + i*4096 + tid*8);
  };

  auto compute = [&](int c){
    const ushort_t* Al = sm + c*16384;
    const ushort_t* Bl = sm + 32768 + c*8192;
    const int s = fr & 7;
    short8 bfr[4][2];
    #pragma unroll
    for (int n=0;n<4;n++){
      const int row = wc*64 + n*16 + fr;
      bfr[n][0] = *(const short8*)(Bl + row*64 + ((kq    ) ^ s)*8);
      bfr[n][1] = *(const short8*)(Bl + row*64 + ((kq + 4) ^ s)*8);
    }
    #pragma unroll
    for (int m=0;m<4;m++){
      const int row = wr*64 + m*16 + fr;
      short8 a0 = *(const short8*)(Al + row*64 + ((kq    ) ^ s)*8);
      short8 a1 = *(const short8*)(Al + row*64 + ((kq + 4) ^ s)*8);
      #pragma unroll
      for (int n=0;n<4;n++){
        acc[m][n] = __builtin_amdgcn_mfma_f32_16x16x32_bf16(a0, bfr[n][0], acc[m][n], 0,0,0);
        acc[m][n] = __builtin_amdgcn_mfma_f32_16x16x32_bf16(a1, bfr[n][1], acc[m][n], 0,0,0);
      }
    }
  };

  const int nkt = K >> 6;
  stage(0, 0);
  stage(1, 1);
  asm volatile("s_waitcnt vmcnt(6)" ::: "memory");
  __builtin_amdgcn_s_barrier();
  __builtin_amdgcn_sched_barrier(0);

  int cur = 0;
  for (int kt = 0; kt < nkt; ++kt){
    compute(cur);
    __builtin_amdgcn_s_barrier();
    __builtin_amdgcn_sched_barrier(0);
    if (kt + 2 < nkt){
      stage(cur, kt + 2);
      asm volatile("s_waitcnt vmcnt(6)" ::: "memory");
    } else {
      asm volatile("s_waitcnt vmcnt(0)" ::: "memory");
    }
    __builtin_amdgcn_s_barrier();
    __builtin_amdgcn_sched_barrier(0);
    cur ^= 1;
  }

  const int rb = m0 + wr*64 + kq*4;
  const int cb = n0 + wc*64 + fr;
  #pragma unroll
  for (int m=0;m<4;m++)
    #pragma unroll
    for (int n=0;n<4;n++){
      const int col = cb + n*16;
      #pragma unroll
      for (int j=0;j<4;j++){
        const int row = rb + m*16 + j;
        float v = acc[m][n][j];
        if (OUTBF) ((ushort_t*)Cp)[(size_t)row*N + col] = f2bf(v);
        else       ((float*)  Cp)[(size_t)row*N + col] = v;
      }
    }
}

// ---------------- GEMM 128x128 (m97 structure) — kept for N=576 (kv_a) ----------
template<bool OUTBF>
__global__ __launch_bounds__(256)
void gemm_bt(const ushort_t* __restrict__ A, const ushort_t* __restrict__ Bw,
             void* __restrict__ Cp, int M, int N, int K, int lda)
{
  __shared__ __attribute__((aligned(16))) ushort_t As[4096];
  __shared__ __attribute__((aligned(16))) ushort_t Bs[4096];
  const int tid = threadIdx.x;
  const int lane = tid & 63;
  const int w = tid >> 6, wr = w >> 1, wc = w & 1;
  const int m0 = blockIdx.y * 128, n0 = blockIdx.x * 128;
  const int fr = lane & 15, kq = lane >> 4;

  f32x4 acc[4][4];
  #pragma unroll
  for (int i=0;i<4;i++)
    #pragma unroll
    for (int j=0;j<4;j++) acc[i][j] = (f32x4){0.f,0.f,0.f,0.f};

  const int sr = tid >> 2;
  const int scc = (tid & 3) * 8;
  const ushort_t* Ag0 = A + (size_t)(m0 + sr) * lda + scc;
  const ushort_t* Ag1 = A + (size_t)(m0 + 64 + sr) * lda + scc;
  const ushort_t* Bg0 = Bw + (size_t)(n0 + sr) * K + scc;
  const ushort_t* Bg1 = Bw + (size_t)(n0 + 64 + sr) * K + scc;
  ushort_t* Al0 = &As[tid*8];
  ushort_t* Al1 = &As[2048 + tid*8];
  ushort_t* Bl0 = &Bs[tid*8];
  ushort_t* Bl1 = &Bs[2048 + tid*8];

  for (int k0 = 0; k0 < K; k0 += 32) {
    gload16(Ag0 + k0, Al0);
    gload16(Ag1 + k0, Al1);
    gload16(Bg0 + k0, Bl0);
    gload16(Bg1 + k0, Bl1);
    __syncthreads();
    short8 a[4], b[4];
    #pragma unroll
    for (int m=0;m<4;m++) a[m] = *(const short8*)&As[(wr*64 + m*16 + fr)*32 + kq*8];
    #pragma unroll
    for (int n=0;n<4;n++) b[n] = *(const short8*)&Bs[(wc*64 + n*16 + fr)*32 + kq*8];
    #pragma unroll
    for (int m=0;m<4;m++)
      #pragma unroll
      for (int n=0;n<4;n++)
        acc[m][n] = __builtin_amdgcn_mfma_f32_16x16x32_bf16(a[m], b[n], acc[m][n], 0, 0, 0);
    __syncthreads();
  }

  const int rb = m0 + wr*64 + kq*4;
  const int cb = n0 + wc*64 + fr;
  #pragma unroll
  for (int m=0;m<4;m++)
    #pragma unroll
    for (int n=0;n<4;n++){
      int col = cb + n*16;
      if (col < N) {
        #pragma unroll
        for (int j=0;j<4;j++){
          int row = rb + m*16 + j;
          float v = acc[m][n][j];
          if (OUTBF) ((ushort_t*)Cp)[(size_t)row*N + col] = f2bf(v);
          else       ((float*)  Cp)[(size_t)row*N + col] = v;
        }
      }
    }
}

// ---------------- RMSNorm in-place on bf16 rows ----------------
__global__ __launch_bounds__(256)
void rmsnorm_ip(ushort_t* __restrict__ x, const float* __restrict__ w, int D, int rowstride){
  const int row = blockIdx.x;
  ushort_t* p = x + (size_t)row * rowstride;
  float ss = 0.f;
  for (int c = threadIdx.x*8; c < D; c += 2048) {
    short8 v = *(const short8*)(p + c);
    #pragma unroll
    for (int j=0;j<8;j++){ float f = bf2f((ushort_t)v[j]); ss += f*f; }
  }
  #pragma unroll
  for (int m=1;m<64;m<<=1) ss += __shfl_xor(ss, m, 64);
  __shared__ float red[4];
  if ((threadIdx.x & 63)==0) red[threadIdx.x>>6] = ss;
  __syncthreads();
  float tot = red[0]+red[1]+red[2]+red[3];
  float inv = rsqrtf(tot/(float)D + 1e-6f);
  for (int c = threadIdx.x*8; c < D; c += 2048) {
    short8 v = *(const short8*)(p + c);
    short8 o;
    #pragma unroll
    for (int j=0;j<8;j++) o[j] = (short)f2bf(bf2f((ushort_t)v[j]) * inv * w[c+j]);
    *(short8*)(p + c) = o;
  }
}

// ---------------- RoPE tables ----------------
__global__ void rope_tab(float* __restrict__ ct, float* __restrict__ st){
  int i = blockIdx.x*256 + threadIdx.x;
  if (i >= Sc*32) return;
  int t = i >> 5, p = i & 31;
  float invf = exp2f(-(float)p * (13.287712379549449f / 32.f));
  float ang = (float)t * invf;
  ct[i] = cosf(ang);
  st[i] = sinf(ang);
}

// ---------------- merged RoPE for q and k ----------------
__global__ void rope_qk(ushort_t* __restrict__ q, ushort_t* __restrict__ ckv,
                        const float* __restrict__ ct, const float* __restrict__ st){
  const int NQ = Bc*Sc*Hc*32;
  int i = blockIdx.x*256 + threadIdx.x;
  if (i < NQ) {
    int p = i & 31, h = (i >> 5) & (Hc-1);
    int bs = i >> 10;
    int t = bs & (Sc-1);
    ushort_t* base = q + (size_t)bs*Hc*QHDc + h*QHDc + NOPEc + 2*p;
    unsigned u = *(const unsigned*)base;
    float a = bf2f((ushort_t)(u & 0xFFFFu)), bb = bf2f((ushort_t)(u >> 16));
    float c = ct[t*32+p], s = st[t*32+p];
    unsigned o = (unsigned)f2bf(a*c - bb*s) | ((unsigned)f2bf(bb*c + a*s) << 16);
    *(unsigned*)base = o;
  } else {
    int k = i - NQ;
    if (k >= Bc*Sc*32) return;
    int p = k & 31;
    int bs = k >> 5;
    int t = bs & (Sc-1);
    ushort_t* base = ckv + (size_t)bs*576 + 512 + 2*p;
    unsigned u = *(const unsigned*)base;
    float a = bf2f((ushort_t)(u & 0xFFFFu)), bb = bf2f((ushort_t)(u >> 16));
    float c = ct[t*32+p], s = st[t*32+p];
    unsigned o = (unsigned)f2bf(a*c - bb*s) | ((unsigned)f2bf(bb*c + a*s) << 16);
    *(unsigned*)base = o;
  }
}

// ---------------- V transpose: kv[bs][h][256](+128) -> vt[bh][vd][s] ----------------
__global__ __launch_bounds__(256)
void vtrans(const ushort_t* __restrict__ kv, ushort_t* __restrict__ vt){
  const int s0 = blockIdx.x * 64;
  const int bh = blockIdx.y;
  const int batch = bh >> 5, h = bh & 31;
  __shared__ __attribute__((aligned(16))) ushort_t L[64][136];
  #pragma unroll
  for (int i = 0; i < 4; i++) {
    int chunk = i*256 + threadIdx.x;
    int r = chunk >> 4;
    int c = (chunk & 15) * 8;
    short8 v = *(const short8*)(kv + ((size_t)(batch*Sc + s0 + r)*Hc + h)*256 + 128 + c);
    *(short8*)&L[r][c] = v;
  }
  __syncthreads();
  #pragma unroll
  for (int i = 0; i < 4; i++) {
    int chunk = i*256 + threadIdx.x;
    int vd = chunk >> 3;
    int sc2 = (chunk & 7) * 8;
    short8 o;
    #pragma unroll
    for (int j=0;j<8;j++) o[j] = (short)L[sc2+j][vd];
    *(short8*)(vt + ((size_t)bh*VDc + vd)*Sc + s0 + sc2) = o;
  }
}

// ---------------- Flash attention (causal), 4 waves x 32 q-rows, 32x32 MFMA ----------
// Block = 128 q-rows, KVBLK=64. Pairing {15-y, y} -> uniform 36 KV-tiles/block.
// Grid 64 bh x 8 = 512 blocks = exactly 2/CU (72 KB LDS). Same-bh blocks are 64
// apart -> same XCD -> correlated KV streaming shares L2.
// K in LDS XOR-swizzled (T2); V via global_load_lds, dbuf, pre-swizzled source
// (rule #21); P through per-wave swizzled LDS; deferred-max/deferred-sum softmax.
__global__ __launch_bounds__(256, 2)
void attn_fwd(const ushort_t* __restrict__ qb, const ushort_t* __restrict__ kvb,
              const ushort_t* __restrict__ ckv, const ushort_t* __restrict__ vt,
              ushort_t* __restrict__ out)
{
  __shared__ __attribute__((aligned(16))) ushort_t Ks[64*192];   // 24 KB, swizzled
  __shared__ __attribute__((aligned(16))) ushort_t Vs[2*8192];   // 32 KB, dbuf [vd][s]
  __shared__ __attribute__((aligned(16))) ushort_t Ps[4*2048];   // 16 KB, per-wave
  const int tid = threadIdx.x, lane = tid & 63, w = tid >> 6;
  const int l31 = lane & 31, hi = lane >> 5;
  const int bh = blockIdx.x, batch = bh >> 5, h = bh & 31;
  const int y = blockIdx.y;

  const float scl = 0.07216878364870323f * 1.4426950408889634f; // 192^-0.5 * log2(e)

  const int ksr = tid >> 2, kci0 = (tid & 3) * 6;   // K staging: 64 rows x 24 chunks

  short8 kreg[6];
  auto loadK = [&](int j0v){
    const ushort_t* kb = kvb + ((size_t)(batch*Sc + j0v + ksr))*((size_t)Hc*256) + h*256;
    const ushort_t* pe = ckv + ((size_t)(batch*Sc + j0v + ksr))*576 + 512;
    #pragma unroll
    for (int i=0;i<6;i++){
      int ci = kci0 + i;
      kreg[i] = (ci < 16) ? *(const short8*)(kb + ci*8)
                          : *(const short8*)(pe + (ci-16)*8);
    }
  };
  auto stageV = [&](int buf, int j0v){
    ushort_t* VB = Vs + buf*8192;
    #pragma unroll
    for (int i=0;i<4;i++){
      int row = w*32 + i*8 + (lane>>3);
      int sc = (lane&7) ^ (row&7);
      gload16(vt + ((size_t)bh*VDc + row)*Sc + j0v + sc*8,
              VB + (w*32 + i*8)*64 + lane*8);
    }
  };

  for (int seg = 0; seg < 2; ++seg) {
    const int p = seg ? y : (15 - y);
    const int q0 = p * 128;
    const int myq0 = q0 + w*32;

    // Q fragments (32 rows x 192 k per wave)
    const ushort_t* qptr = qb + ((size_t)(batch*Sc + myq0 + l31)*Hc + h)*QHDc;
    short8 qf[12];
    #pragma unroll
    for (int kk=0;kk<12;kk++) qf[kk] = *(const short8*)(qptr + kk*16 + (hi<<3));

    f32x16 acc[4];
    #pragma unroll
    for (int gv=0;gv<4;gv++) acc[gv] = f32x16{};
    float mrow[16], lpart[16];
    #pragma unroll
    for (int j=0;j<16;j++){ mrow[j] = -3e38f; lpart[j] = 0.f; }

    const int ktiles = 2*p + 2;
    int cur = 0;
    loadK(0);
    stageV(0, 0);

    for (int kt = 0; kt < ktiles; kt++) {
      const int j0 = kt*64;
      // publish K (swizzled)
      #pragma unroll
      for (int i=0;i<6;i++){
        int ci = kci0 + i;
        *(short8*)&Ks[ksr*192 + ((ci ^ (ksr&7))<<3)] = kreg[i];
      }
      __syncthreads();   // drains this tile's V gloads too

      if (kt + 1 < ktiles){ loadK(j0+64); stageV(cur^1, j0+64); }
      const ushort_t* VB = Vs + cur*8192;
      const ushort_t* PW = Ps + w*2048;

      if (j0 <= myq0 + 31) {           // wave-uniform: skip fully-masked tiles
        // QK^T: 32q x 64kv via 2 groups of 32x32
        f32x16 sA{}, sB{};
        __builtin_amdgcn_s_setprio(1);
        #pragma unroll
        for (int kk=0;kk<12;kk++){
          const int ch = (((kk*2 + hi) ^ (l31&7))<<3);
          short8 b0 = *(const short8*)&Ks[l31*192 + ch];
          short8 b1 = *(const short8*)&Ks[(32+l31)*192 + ch];
          sA = __builtin_amdgcn_mfma_f32_32x32x16_bf16(qf[kk], b0, sA, 0,0,0);
          sB = __builtin_amdgcn_mfma_f32_32x32x16_bf16(qf[kk], b1, sB, 0,0,0);
        }
        __builtin_amdgcn_s_setprio(0);

        const bool fullt = (j0 + 63 <= myq0);
        int okl = 1;
        #pragma unroll
        for (int j=0;j<16;j++){
          float a = sA[j]*scl, b = sB[j]*scl;
          if (!fullt){
            const int r = (j&3) + ((j>>2)<<3) + (hi<<2);
            const int qp = myq0 + r;
            if (j0 + l31      > qp) a = -3e38f;
            if (j0 + 32 + l31 > qp) b = -3e38f;
          }
          sA[j] = a; sB[j] = b;
          okl &= (fmaxf(a,b) <= mrow[j] + 8.0f) ? 1 : 0;
        }
        if (!__all(okl)) {
          float tm[16];
          #pragma unroll
          for (int j=0;j<16;j++) tm[j] = fmaxf(sA[j], sB[j]);
          #pragma unroll
          for (int m=1;m<32;m<<=1){
            #pragma unroll
            for (int j=0;j<16;j++) tm[j] = fmaxf(tm[j], __shfl_xor(tm[j], m, 64));
          }
          #pragma unroll
          for (int j=0;j<16;j++){
            float mn = fmaxf(mrow[j], tm[j]);
            float c = exp2f(mrow[j] - mn);
            mrow[j] = mn; lpart[j] *= c;
            acc[0][j]*=c; acc[1][j]*=c; acc[2][j]*=c; acc[3][j]*=c;
          }
        }
        #pragma unroll
        for (int j=0;j<16;j++){
          float pa = exp2f(sA[j] - mrow[j]);
          float pb = exp2f(sB[j] - mrow[j]);
          lpart[j] += pa + pb;
          const int r = (j&3) + ((j>>2)<<3) + (hi<<2);
          const int cA = l31, cB = 32 + l31;
          ((ushort_t*)PW)[r*64 + (((cA>>3) ^ (r&7))<<3) + (cA&7)] = f2bf(pa);
          ((ushort_t*)PW)[r*64 + (((cB>>3) ^ (r&7))<<3) + (cB&7)] = f2bf(pb);
        }
        // PV: O[32q x 128vd] += P[32q x 64kv] * V
        __builtin_amdgcn_s_setprio(1);
        #pragma unroll
        for (int kkk=0; kkk<4; ++kkk){
          const int ch = (((kkk*2 + hi) ^ (l31&7))<<3);
          short8 ap = *(const short8*)&PW[l31*64 + ch];
          #pragma unroll
          for (int gv=0; gv<4; ++gv){
            short8 bv = *(const short8*)&VB[(gv*32 + l31)*64 + ch];
            acc[gv] = __builtin_amdgcn_mfma_f32_32x32x16_bf16(ap, bv, acc[gv], 0,0,0);
          }
        }
        __builtin_amdgcn_s_setprio(0);
      }
      __syncthreads();
      cur ^= 1;
    }

    // epilogue: reduce denominators (rows live in 32-lane halves) and store O
    #pragma unroll
    for (int m=1;m<32;m<<=1){
      #pragma unroll
      for (int j=0;j<16;j++) lpart[j] += __shfl_xor(lpart[j], m, 64);
    }
    #pragma unroll
    for (int gv=0; gv<4; ++gv){
      #pragma unroll
      for (int j=0;j<16;j++){
        const int r = (j&3) + ((j>>2)<<3) + (hi<<2);
        const int qg = myq0 + r;
        out[(size_t)(batch*Sc + qg)*(Hc*VDc) + h*VDc + gv*32 + l31] = f2bf(acc[gv][j]/lpart[j]);
      }
    }
  }
}

// ---------------- launcher ----------------
extern "C" void kernel_launch(void* const* d_in, const int* in_sizes, int n_in,
                              void* d_out, int out_size, void* d_ws, size_t ws_size,
                              hipStream_t stream) {
  (void)in_sizes; (void)n_in; (void)out_size; (void)ws_size;
  const float* hidden  = (const float*)d_in[0];
  const float* q_a_w   = (const float*)d_in[3];
  const float* q_a_ln  = (const float*)d_in[4];
  const float* q_b_w   = (const float*)d_in[5];
  const float* kv_a_w  = (const float*)d_in[6];
  const float* kv_a_ln = (const float*)d_in[7];
  const float* kv_b_w  = (const float*)d_in[8];
  const float* o_w     = (const float*)d_in[9];
  float* outp = (float*)d_out;

  char* ws = (char*)d_ws;
  size_t off = 0;
  auto alloc = [&](size_t n)->char*{ char* p = ws + off; off += (n + 255) & ~(size_t)255; return p; };
  ushort_t* hbf  = (ushort_t*)alloc((size_t)Bc*Sc*HIDc*2);      // hidden bf16; later o_w bf16
  ushort_t* wqa  = (ushort_t*)alloc((size_t)QLRc*HIDc*2);       // later aliased as aout
  ushort_t* wqb  = (ushort_t*)alloc((size_t)Hc*QHDc*QLRc*2);
  ushort_t* wkva = (ushort_t*)alloc((size_t)640*HIDc*2);        // padded rows (over-read)
  ushort_t* wkvb = (ushort_t*)alloc((size_t)Hc*256*KVLRc*2);
  ushort_t* qa   = (ushort_t*)alloc((size_t)Bc*Sc*QLRc*2);
  ushort_t* qbf  = (ushort_t*)alloc((size_t)Bc*Sc*Hc*QHDc*2);
  ushort_t* ckv  = (ushort_t*)alloc((size_t)Bc*Sc*576*2);
  ushort_t* kvbf = (ushort_t*)alloc((size_t)Bc*Sc*Hc*256*2);
  ushort_t* vtb  = (ushort_t*)alloc((size_t)Bc*Hc*VDc*Sc*2);    // V transposed [bh][vd][s]
  float*    ct   = (float*)alloc((size_t)Sc*32*4);
  float*    st   = (float*)alloc((size_t)Sc*32*4);
  ushort_t* aout = wqa;   // alias: wqa+wqb+wkva (36.7 MB) free before attn; aout = 33.5 MB

  const int M = Bc*Sc; // 4096

  // one batched convert: hidden + q_a_w + q_b_w + kv_a_w + kv_b_w
  conv_all<<<2048,256,0,stream>>>(hidden, q_a_w, q_b_w, kv_a_w, kv_b_w,
                                  hbf, wqa, wqb, wkva, wkvb);
  // q_a = hidden @ q_a_w^T   [4096,1536,4096]
  gemm256x128<true><<<(M/256)*(QLRc/128),512,0,stream>>>(hbf, wqa, qa, M, QLRc, HIDc, HIDc);
  // ckv = hidden @ kv_a_w^T  (N=576 -> 128^2 kernel, bounds-checked cols)
  gemm_bt<true><<<dim3(5, M/128),256,0,stream>>>(hbf, wkva, ckv, M, KVLRc+ROPEc, HIDc, HIDc);
  rmsnorm_ip<<<M,256,0,stream>>>(qa, q_a_ln, QLRc, QLRc);
  rmsnorm_ip<<<M,256,0,stream>>>(ckv, kv_a_ln, KVLRc, 576);
  // hbf free now -> convert o_w into it
  f32_to_bf16<<<2048,256,0,stream>>>(o_w, hbf, (long long)HIDc*HIDc);
  // q = q_a @ q_b_w^T  [4096,6144,1536]
  gemm256x128<true><<<(M/256)*(Hc*QHDc/128),512,0,stream>>>(qa, wqb, qbf, M, Hc*QHDc, QLRc, QLRc);
  // kv = ckv_norm @ kv_b_w^T  [4096,8192,512] (coalesced C)
  gemm256<true><<<(M/256)*(Hc*256/256),512,0,stream>>>(ckv, wkvb, kvbf, M, Hc*256, KVLRc, 576);
  // RoPE
  rope_tab<<<CDIV(Sc*32,256),256,0,stream>>>(ct, st);
  rope_qk<<<CDIV(Bc*Sc*Hc*32 + Bc*Sc*32,256),256,0,stream>>>(qbf, ckv, ct, st);
  // V transpose + attention (512 uniform blocks = 2/CU exact)
  vtrans<<<dim3(Sc/64, Bc*Hc),256,0,stream>>>(kvbf, vtb);
  attn_fwd<<<dim3(Bc*Hc, 8),256,0,stream>>>(qbf, kvbf, ckv, vtb, aout);
  // out = attn @ o_w^T  [4096,4096,4096], f32 store
  gemm256<false><<<(M/256)*(HIDc/256),512,0,stream>>>(aout, hbf, outp, M, HIDc, HIDc, HIDc);
}

// Round 8
// 701.731 us; speedup vs baseline: 1.5363x; 1.5363x over previous
//
#include <hip/hip_runtime.h>
#include <hip/hip_bf16.h>

typedef __attribute__((ext_vector_type(8))) short short8;
typedef __attribute__((ext_vector_type(4))) float f32x4;
typedef unsigned short ushort_t;

static constexpr int Bc = 2, Sc = 2048, HIDc = 4096, Hc = 32;
static constexpr int NOPEc = 128, ROPEc = 64, VDc = 128, QHDc = 192;
static constexpr int QLRc = 1536, KVLRc = 512;

#define CDIV(a,b) (((a)+(b)-1)/(b))

__device__ __forceinline__ float bf2f(ushort_t u){
  union { unsigned u32; float f; } x; x.u32 = ((unsigned)u) << 16; return x.f;
}
__device__ __forceinline__ ushort_t f2bf(float f){
  union { float f; unsigned u32; } x; x.f = f;
  unsigned r = x.u32 + 0x7FFFu + ((x.u32 >> 16) & 1u);
  return (ushort_t)(r >> 16);
}
__device__ __forceinline__ void gload16(const void* g, void* l){
  __builtin_amdgcn_global_load_lds((const __attribute__((address_space(1))) void*)g,
                                   (__attribute__((address_space(3))) void*)l, 16, 0, 0);
}

// ---------------- f32 -> bf16 convert (vectorized, grid-stride) ----------------
__global__ __launch_bounds__(256)
void f32_to_bf16(const float* __restrict__ in, ushort_t* __restrict__ out, long long n){
  long long stride = (long long)gridDim.x * 256 * 4;
  for (long long i = ((long long)blockIdx.x*256 + threadIdx.x)*4; i < n; i += stride){
    float4 v = *(const float4*)(in + i);
    unsigned long long pk = (unsigned long long)f2bf(v.x)
                          | ((unsigned long long)f2bf(v.y) << 16)
                          | ((unsigned long long)f2bf(v.z) << 32)
                          | ((unsigned long long)f2bf(v.w) << 48);
    *(unsigned long long*)(out + i) = pk;
  }
}

// ---------------- batched 5-segment f32->bf16 (hidden + 4 weights) ----------------
__global__ __launch_bounds__(256)
void conv_all(const float* __restrict__ s0, const float* __restrict__ s1,
              const float* __restrict__ s2, const float* __restrict__ s3,
              const float* __restrict__ s4,
              ushort_t* __restrict__ d0, ushort_t* __restrict__ d1,
              ushort_t* __restrict__ d2, ushort_t* __restrict__ d3,
              ushort_t* __restrict__ d4){
  constexpr long long C0 = 16777216, C1 = 23068672, C2 = 32505856, C3 = 34865152, C4 = 39059456;
  long long stride = (long long)gridDim.x * 256 * 4;
  for (long long e = ((long long)blockIdx.x*256 + threadIdx.x)*4; e < C4; e += stride){
    const float* sp; ushort_t* dp; long long o;
    if      (e < C0){ sp = s0; dp = d0; o = e; }
    else if (e < C1){ sp = s1; dp = d1; o = e - C0; }
    else if (e < C2){ sp = s2; dp = d2; o = e - C1; }
    else if (e < C3){ sp = s3; dp = d3; o = e - C2; }
    else            { sp = s4; dp = d4; o = e - C3; }
    float4 v = *(const float4*)(sp + o);
    unsigned long long pk = (unsigned long long)f2bf(v.x)
                          | ((unsigned long long)f2bf(v.y) << 16)
                          | ((unsigned long long)f2bf(v.z) << 32)
                          | ((unsigned long long)f2bf(v.w) << 48);
    *(unsigned long long*)(dp + o) = pk;
  }
}

// ======== GEMM 256x256 tile, BK=64, 8 waves, dbuf LDS, swizzled, counted vmcnt ======
template<bool OUTBF>
__global__ __launch_bounds__(512, 2)
void gemm256(const ushort_t* __restrict__ A, const ushort_t* __restrict__ Bw,
             void* __restrict__ Cp, int M, int N, int K, int lda)
{
  __shared__ __attribute__((aligned(16))) ushort_t sm[65536];
  const int tid = threadIdx.x, lane = tid & 63, w = tid >> 6;
  const int wr = w >> 2, wc = w & 3;
  const int fr = lane & 15, kq = lane >> 4;

  const int nwg = gridDim.x, nx = N >> 8;
  const int bid = blockIdx.x;
  const int swz = (bid & 7) * (nwg >> 3) + (bid >> 3);
  const int m0 = (swz / nx) << 8, n0 = (swz % nx) << 8;

  f32x4 acc[8][4];
  #pragma unroll
  for (int m=0;m<8;m++)
    #pragma unroll
    for (int n=0;n<4;n++) acc[m][n] = (f32x4){0.f,0.f,0.f,0.f};

  const int srow = tid >> 3;
  const int gch  = (tid & 7) ^ (srow & 7);

  auto stage = [&](int c, int kt){
    const int k0 = kt << 6;
    ushort_t* Al = sm + c*16384;
    ushort_t* Bl = sm + 32768 + c*16384;
    const ushort_t* Ag = A  + (size_t)(m0 + srow)*lda + k0 + gch*8;
    const ushort_t* Bg = Bw + (size_t)(n0 + srow)*K   + k0 + gch*8;
    #pragma unroll
    for (int i=0;i<4;i++) gload16(Ag + (size_t)(i*64)*lda, Al + i*4096 + tid*8);
    #pragma unroll
    for (int i=0;i<4;i++) gload16(Bg + (size_t)(i*64)*K,   Bl + i*4096 + tid*8);
  };

  auto compute = [&](int c){
    const ushort_t* Al = sm + c*16384;
    const ushort_t* Bl = sm + 32768 + c*16384;
    const int s = fr & 7;
    short8 bfr[4][2];
    #pragma unroll
    for (int n=0;n<4;n++){
      const int row = wc*64 + n*16 + fr;
      bfr[n][0] = *(const short8*)(Bl + row*64 + ((kq    ) ^ s)*8);
      bfr[n][1] = *(const short8*)(Bl + row*64 + ((kq + 4) ^ s)*8);
    }
    #pragma unroll
    for (int m=0;m<8;m++){
      const int row = wr*128 + m*16 + fr;
      short8 a0 = *(const short8*)(Al + row*64 + ((kq    ) ^ s)*8);
      short8 a1 = *(const short8*)(Al + row*64 + ((kq + 4) ^ s)*8);
      #pragma unroll
      for (int n=0;n<4;n++){
        acc[m][n] = __builtin_amdgcn_mfma_f32_16x16x32_bf16(a0, bfr[n][0], acc[m][n], 0,0,0);
        acc[m][n] = __builtin_amdgcn_mfma_f32_16x16x32_bf16(a1, bfr[n][1], acc[m][n], 0,0,0);
      }
    }
  };

  const int nkt = K >> 6;
  stage(0, 0);
  stage(1, 1);
  asm volatile("s_waitcnt vmcnt(8)" ::: "memory");
  __builtin_amdgcn_s_barrier();
  __builtin_amdgcn_sched_barrier(0);

  int cur = 0;
  for (int kt = 0; kt < nkt; ++kt){
    compute(cur);
    __builtin_amdgcn_s_barrier();
    __builtin_amdgcn_sched_barrier(0);
    if (kt + 2 < nkt){
      stage(cur, kt + 2);
      asm volatile("s_waitcnt vmcnt(8)" ::: "memory");
    } else {
      asm volatile("s_waitcnt vmcnt(0)" ::: "memory");
    }
    __builtin_amdgcn_s_barrier();
    __builtin_amdgcn_sched_barrier(0);
    cur ^= 1;
  }

  const int rb = m0 + wr*128 + kq*4;
  const int cb = n0 + wc*64 + fr;
  #pragma unroll
  for (int m=0;m<8;m++)
    #pragma unroll
    for (int n=0;n<4;n++){
      const int col = cb + n*16;
      #pragma unroll
      for (int j=0;j<4;j++){
        const int row = rb + m*16 + j;
        float v = acc[m][n][j];
        if (OUTBF) ((ushort_t*)Cp)[(size_t)row*N + col] = f2bf(v);
        else       ((float*)  Cp)[(size_t)row*N + col] = v;
      }
    }
}

// ======== GEMM 256x128 tile, BK=64, 8 waves (4Mx2N), dbuf, counted vmcnt ======
template<bool OUTBF>
__global__ __launch_bounds__(512, 2)
void gemm256x128(const ushort_t* __restrict__ A, const ushort_t* __restrict__ Bw,
                 void* __restrict__ Cp, int M, int N, int K, int lda)
{
  __shared__ __attribute__((aligned(16))) ushort_t sm[49152];
  const int tid = threadIdx.x, lane = tid & 63, w = tid >> 6;
  const int wr = w >> 1, wc = w & 1;
  const int fr = lane & 15, kq = lane >> 4;

  const int nwg = gridDim.x, nx = N >> 7;
  const int bid = blockIdx.x;
  const int swz = (bid & 7) * (nwg >> 3) + (bid >> 3);
  const int m0 = (swz / nx) << 8, n0 = (swz % nx) << 7;

  f32x4 acc[4][4];
  #pragma unroll
  for (int m=0;m<4;m++)
    #pragma unroll
    for (int n=0;n<4;n++) acc[m][n] = (f32x4){0.f,0.f,0.f,0.f};

  const int srow = tid >> 3;
  const int gch  = (tid & 7) ^ (srow & 7);

  auto stage = [&](int c, int kt){
    const int k0 = kt << 6;
    ushort_t* Al = sm + c*16384;
    ushort_t* Bl = sm + 32768 + c*8192;
    const ushort_t* Ag = A  + (size_t)(m0 + srow)*lda + k0 + gch*8;
    const ushort_t* Bg = Bw + (size_t)(n0 + srow)*K   + k0 + gch*8;
    #pragma unroll
    for (int i=0;i<4;i++) gload16(Ag + (size_t)(i*64)*lda, Al + i*4096 + tid*8);
    #pragma unroll
    for (int i=0;i<2;i++) gload16(Bg + (size_t)(i*64)*K,   Bl + i*4096 + tid*8);
  };

  auto compute = [&](int c){
    const ushort_t* Al = sm + c*16384;
    const ushort_t* Bl = sm + 32768 + c*8192;
    const int s = fr & 7;
    short8 bfr[4][2];
    #pragma unroll
    for (int n=0;n<4;n++){
      const int row = wc*64 + n*16 + fr;
      bfr[n][0] = *(const short8*)(Bl + row*64 + ((kq    ) ^ s)*8);
      bfr[n][1] = *(const short8*)(Bl + row*64 + ((kq + 4) ^ s)*8);
    }
    #pragma unroll
    for (int m=0;m<4;m++){
      const int row = wr*64 + m*16 + fr;
      short8 a0 = *(const short8*)(Al + row*64 + ((kq    ) ^ s)*8);
      short8 a1 = *(const short8*)(Al + row*64 + ((kq + 4) ^ s)*8);
      #pragma unroll
      for (int n=0;n<4;n++){
        acc[m][n] = __builtin_amdgcn_mfma_f32_16x16x32_bf16(a0, bfr[n][0], acc[m][n], 0,0,0);
        acc[m][n] = __builtin_amdgcn_mfma_f32_16x16x32_bf16(a1, bfr[n][1], acc[m][n], 0,0,0);
      }
    }
  };

  const int nkt = K >> 6;
  stage(0, 0);
  stage(1, 1);
  asm volatile("s_waitcnt vmcnt(6)" ::: "memory");
  __builtin_amdgcn_s_barrier();
  __builtin_amdgcn_sched_barrier(0);

  int cur = 0;
  for (int kt = 0; kt < nkt; ++kt){
    compute(cur);
    __builtin_amdgcn_s_barrier();
    __builtin_amdgcn_sched_barrier(0);
    if (kt + 2 < nkt){
      stage(cur, kt + 2);
      asm volatile("s_waitcnt vmcnt(6)" ::: "memory");
    } else {
      asm volatile("s_waitcnt vmcnt(0)" ::: "memory");
    }
    __builtin_amdgcn_s_barrier();
    __builtin_amdgcn_sched_barrier(0);
    cur ^= 1;
  }

  const int rb = m0 + wr*64 + kq*4;
  const int cb = n0 + wc*64 + fr;
  #pragma unroll
  for (int m=0;m<4;m++)
    #pragma unroll
    for (int n=0;n<4;n++){
      const int col = cb + n*16;
      #pragma unroll
      for (int j=0;j<4;j++){
        const int row = rb + m*16 + j;
        float v = acc[m][n][j];
        if (OUTBF) ((ushort_t*)Cp)[(size_t)row*N + col] = f2bf(v);
        else       ((float*)  Cp)[(size_t)row*N + col] = v;
      }
    }
}

// ---------------- GEMM 128x128 (m97 structure) — kept for N=576 (kv_a) ----------
template<bool OUTBF>
__global__ __launch_bounds__(256)
void gemm_bt(const ushort_t* __restrict__ A, const ushort_t* __restrict__ Bw,
             void* __restrict__ Cp, int M, int N, int K, int lda)
{
  __shared__ __attribute__((aligned(16))) ushort_t As[4096];
  __shared__ __attribute__((aligned(16))) ushort_t Bs[4096];
  const int tid = threadIdx.x;
  const int lane = tid & 63;
  const int w = tid >> 6, wr = w >> 1, wc = w & 1;
  const int m0 = blockIdx.y * 128, n0 = blockIdx.x * 128;
  const int fr = lane & 15, kq = lane >> 4;

  f32x4 acc[4][4];
  #pragma unroll
  for (int i=0;i<4;i++)
    #pragma unroll
    for (int j=0;j<4;j++) acc[i][j] = (f32x4){0.f,0.f,0.f,0.f};

  const int sr = tid >> 2;
  const int scc = (tid & 3) * 8;
  const ushort_t* Ag0 = A + (size_t)(m0 + sr) * lda + scc;
  const ushort_t* Ag1 = A + (size_t)(m0 + 64 + sr) * lda + scc;
  const ushort_t* Bg0 = Bw + (size_t)(n0 + sr) * K + scc;
  const ushort_t* Bg1 = Bw + (size_t)(n0 + 64 + sr) * K + scc;
  ushort_t* Al0 = &As[tid*8];
  ushort_t* Al1 = &As[2048 + tid*8];
  ushort_t* Bl0 = &Bs[tid*8];
  ushort_t* Bl1 = &Bs[2048 + tid*8];

  for (int k0 = 0; k0 < K; k0 += 32) {
    gload16(Ag0 + k0, Al0);
    gload16(Ag1 + k0, Al1);
    gload16(Bg0 + k0, Bl0);
    gload16(Bg1 + k0, Bl1);
    __syncthreads();
    short8 a[4], b[4];
    #pragma unroll
    for (int m=0;m<4;m++) a[m] = *(const short8*)&As[(wr*64 + m*16 + fr)*32 + kq*8];
    #pragma unroll
    for (int n=0;n<4;n++) b[n] = *(const short8*)&Bs[(wc*64 + n*16 + fr)*32 + kq*8];
    #pragma unroll
    for (int m=0;m<4;m++)
      #pragma unroll
      for (int n=0;n<4;n++)
        acc[m][n] = __builtin_amdgcn_mfma_f32_16x16x32_bf16(a[m], b[n], acc[m][n], 0, 0, 0);
    __syncthreads();
  }

  const int rb = m0 + wr*64 + kq*4;
  const int cb = n0 + wc*64 + fr;
  #pragma unroll
  for (int m=0;m<4;m++)
    #pragma unroll
    for (int n=0;n<4;n++){
      int col = cb + n*16;
      if (col < N) {
        #pragma unroll
        for (int j=0;j<4;j++){
          int row = rb + m*16 + j;
          float v = acc[m][n][j];
          if (OUTBF) ((ushort_t*)Cp)[(size_t)row*N + col] = f2bf(v);
          else       ((float*)  Cp)[(size_t)row*N + col] = v;
        }
      }
    }
}

// ---------------- merged RMSNorm (qa rows then ckv rows) ----------------
__global__ __launch_bounds__(256)
void rmsnorm2(ushort_t* __restrict__ xa, const float* __restrict__ wa,
              ushort_t* __restrict__ xb, const float* __restrict__ wb){
  const int row = blockIdx.x;
  ushort_t* p; const float* w; int D;
  if (row < Bc*Sc){ p = xa + (size_t)row*QLRc; w = wa; D = QLRc; }
  else            { p = xb + (size_t)(row - Bc*Sc)*576; w = wb; D = KVLRc; }
  float ss = 0.f;
  for (int c = threadIdx.x*8; c < D; c += 2048) {
    short8 v = *(const short8*)(p + c);
    #pragma unroll
    for (int j=0;j<8;j++){ float f = bf2f((ushort_t)v[j]); ss += f*f; }
  }
  #pragma unroll
  for (int m=1;m<64;m<<=1) ss += __shfl_xor(ss, m, 64);
  __shared__ float red[4];
  if ((threadIdx.x & 63)==0) red[threadIdx.x>>6] = ss;
  __syncthreads();
  float tot = red[0]+red[1]+red[2]+red[3];
  float inv = rsqrtf(tot/(float)D + 1e-6f);
  for (int c = threadIdx.x*8; c < D; c += 2048) {
    short8 v = *(const short8*)(p + c);
    short8 o;
    #pragma unroll
    for (int j=0;j<8;j++) o[j] = (short)f2bf(bf2f((ushort_t)v[j]) * inv * w[c+j]);
    *(short8*)(p + c) = o;
  }
}

// ---------------- RoPE tables ----------------
__global__ void rope_tab(float* __restrict__ ct, float* __restrict__ st){
  int i = blockIdx.x*256 + threadIdx.x;
  if (i >= Sc*32) return;
  int t = i >> 5, p = i & 31;
  float invf = exp2f(-(float)p * (13.287712379549449f / 32.f));
  float ang = (float)t * invf;
  ct[i] = cosf(ang);
  st[i] = sinf(ang);
}

// ---------------- merged RoPE for q and k ----------------
__global__ void rope_qk(ushort_t* __restrict__ q, ushort_t* __restrict__ ckv,
                        const float* __restrict__ ct, const float* __restrict__ st){
  const int NQ = Bc*Sc*Hc*32;
  int i = blockIdx.x*256 + threadIdx.x;
  if (i < NQ) {
    int p = i & 31, h = (i >> 5) & (Hc-1);
    int bs = i >> 10;
    int t = bs & (Sc-1);
    ushort_t* base = q + (size_t)bs*Hc*QHDc + h*QHDc + NOPEc + 2*p;
    unsigned u = *(const unsigned*)base;
    float a = bf2f((ushort_t)(u & 0xFFFFu)), bb = bf2f((ushort_t)(u >> 16));
    float c = ct[t*32+p], s = st[t*32+p];
    unsigned o = (unsigned)f2bf(a*c - bb*s) | ((unsigned)f2bf(bb*c + a*s) << 16);
    *(unsigned*)base = o;
  } else {
    int k = i - NQ;
    if (k >= Bc*Sc*32) return;
    int p = k & 31;
    int bs = k >> 5;
    int t = bs & (Sc-1);
    ushort_t* base = ckv + (size_t)bs*576 + 512 + 2*p;
    unsigned u = *(const unsigned*)base;
    float a = bf2f((ushort_t)(u & 0xFFFFu)), bb = bf2f((ushort_t)(u >> 16));
    float c = ct[t*32+p], s = st[t*32+p];
    unsigned o = (unsigned)f2bf(a*c - bb*s) | ((unsigned)f2bf(bb*c + a*s) << 16);
    *(unsigned*)base = o;
  }
}

// ---------------- V transpose: kv[bs][h][256](+128) -> vt[bh][vd][s] ----------------
__global__ __launch_bounds__(256)
void vtrans(const ushort_t* __restrict__ kv, ushort_t* __restrict__ vt){
  const int s0 = blockIdx.x * 64;
  const int bh = blockIdx.y;
  const int batch = bh >> 5, h = bh & 31;
  __shared__ __attribute__((aligned(16))) ushort_t L[64][136];
  #pragma unroll
  for (int i = 0; i < 4; i++) {
    int chunk = i*256 + threadIdx.x;
    int r = chunk >> 4;
    int c = (chunk & 15) * 8;
    short8 v = *(const short8*)(kv + ((size_t)(batch*Sc + s0 + r)*Hc + h)*256 + 128 + c);
    *(short8*)&L[r][c] = v;
  }
  __syncthreads();
  #pragma unroll
  for (int i = 0; i < 4; i++) {
    int chunk = i*256 + threadIdx.x;
    int vd = chunk >> 3;
    int sc2 = (chunk & 7) * 8;
    short8 o;
    #pragma unroll
    for (int j=0;j<8;j++) o[j] = (short)L[sc2+j][vd];
    *(short8*)(vt + ((size_t)bh*VDc + vd)*Sc + s0 + sc2) = o;
  }
}

// ---------------- Flash attention (causal), 4 waves — PROVEN 212us version ----------
// Diagonal pairing: block (bh, y) processes q-tiles {31-y, y} sequentially ->
// every block does exactly 66 KV-tile iterations (perfect balance); same-bh blocks
// stream K/V in lockstep from t=0 -> near-perfect L2 reuse (FETCH ~107MB).
__global__ __launch_bounds__(256)
void attn_fwd(const ushort_t* __restrict__ qb, const ushort_t* __restrict__ kvb,
              const ushort_t* __restrict__ ckv, const ushort_t* __restrict__ vt,
              ushort_t* __restrict__ out)
{
  constexpr int KP = 200, VP = 40;   // padded strides: 2-way-bank-conflict only
  __shared__ __attribute__((aligned(16))) ushort_t Ks[32*KP];
  __shared__ __attribute__((aligned(16))) ushort_t Vs[128*VP];
  __shared__ __attribute__((aligned(16))) ushort_t Ps[4][16*VP];
  const int tid = threadIdx.x, lane = tid & 63, w = tid >> 6;
  const int fr = lane & 15, kq = lane >> 4;
  const int y = (int)blockIdx.y;                      // 0..15
  const int bh = blockIdx.x, batch = bh >> 5, h = bh & 31;

  const float scl = 0.07216878364870323f * 1.4426950408889634f; // 192^-0.5 * log2(e)
  const float THR = 8.0f;

  const int ksr = tid >> 3, ksub = tid & 7;   // K staging: 32 rows x 24 chunks
  const int vvd = tid >> 1, vsub = tid & 1;   // V staging: 128 rows x 4 chunks

  const ushort_t* kbase  = kvb + ((size_t)batch*Sc + ksr)*((size_t)Hc*256) + (size_t)h*256;
  const ushort_t* pebase = ckv + (size_t)(batch*Sc + ksr)*576 + 512;
  const ushort_t* vbase  = vt + ((size_t)bh*VDc + vvd)*Sc;

  for (int seg = 0; seg < 2; ++seg) {
    const int qt = seg == 0 ? (31 - y) : y;           // heavy tile first
    const int q0 = qt * 64;

    const int qrow = q0 + w*16 + fr;
    const ushort_t* qptr = qb + ((size_t)(batch*Sc + qrow)*Hc + h)*QHDc;
    short8 qf[6];
    #pragma unroll
    for (int kk=0;kk<6;kk++) qf[kk] = *(const short8*)(qptr + kk*32 + kq*8);

    f32x4 acc_o[8];
    #pragma unroll
    for (int i=0;i<8;i++) acc_o[i] = (f32x4){0.f,0.f,0.f,0.f};
    float mrow[4]  = {-3e38f,-3e38f,-3e38f,-3e38f};
    float lpart[4] = {0.f,0.f,0.f,0.f};

    const int ktiles = q0/32 + 2;

    short8 kreg[3], vreg[2];
    {
      #pragma unroll
      for (int i=0;i<3;i++){
        int c = (ksub*3 + i)*8;
        kreg[i] = (c < 128) ? *(const short8*)(kbase + c)
                            : *(const short8*)(pebase + (c - 128));
      }
      #pragma unroll
      for (int i=0;i<2;i++) vreg[i] = *(const short8*)(vbase + (vsub*2+i)*8);
    }

    for (int kt = 0; kt < ktiles; kt++) {
      const int j0 = kt*32;
      #pragma unroll
      for (int i=0;i<3;i++) *(short8*)&Ks[ksr*KP + (ksub*3 + i)*8] = kreg[i];
      #pragma unroll
      for (int i=0;i<2;i++) *(short8*)&Vs[vvd*VP + (vsub*2 + i)*8] = vreg[i];
      __syncthreads();

      if (kt + 1 < ktiles) {
        const size_t roff = (size_t)(j0 + 32);
        #pragma unroll
        for (int i=0;i<3;i++){
          int c = (ksub*3 + i)*8;
          kreg[i] = (c < 128) ? *(const short8*)(kbase + roff*((size_t)Hc*256) + c)
                              : *(const short8*)(pebase + roff*576 + (c - 128));
        }
        #pragma unroll
        for (int i=0;i<2;i++) vreg[i] = *(const short8*)(vbase + roff + (vsub*2+i)*8);
      }

      f32x4 s0 = (f32x4){0.f,0.f,0.f,0.f}, s1 = (f32x4){0.f,0.f,0.f,0.f};
      __builtin_amdgcn_s_setprio(1);
      #pragma unroll
      for (int kk=0;kk<6;kk++){
        short8 b0 = *(const short8*)&Ks[fr*KP + kk*32 + kq*8];
        short8 b1 = *(const short8*)&Ks[(16+fr)*KP + kk*32 + kq*8];
        s0 = __builtin_amdgcn_mfma_f32_16x16x32_bf16(qf[kk], b0, s0, 0,0,0);
        s1 = __builtin_amdgcn_mfma_f32_16x16x32_bf16(qf[kk], b1, s1, 0,0,0);
      }
      __builtin_amdgcn_s_setprio(0);

      const bool full = (j0 + 31 <= q0 + w*16);
      float x0[4], x1[4];
      int okl = 1;
      #pragma unroll
      for (int j=0;j<4;j++){
        float a  = s0[j]*scl, c2 = s1[j]*scl;
        if (!full) {
          int qp = q0 + w*16 + kq*4 + j;
          if (j0 + fr      > qp) a  = -3e38f;
          if (j0 + 16 + fr > qp) c2 = -3e38f;
        }
        x0[j] = a; x1[j] = c2;
        okl &= (fmaxf(a, c2) <= mrow[j] + THR) ? 1 : 0;
      }
      if (!__all(okl)) {
        float tmax[4];
        #pragma unroll
        for (int j=0;j<4;j++) tmax[j] = fmaxf(x0[j], x1[j]);
        #pragma unroll
        for (int m=1;m<16;m<<=1){
          #pragma unroll
          for (int j=0;j<4;j++) tmax[j] = fmaxf(tmax[j], __shfl_xor(tmax[j], m, 64));
        }
        #pragma unroll
        for (int j=0;j<4;j++){
          float mn = fmaxf(mrow[j], tmax[j]);
          float corr = exp2f(mrow[j] - mn);
          mrow[j] = mn;
          lpart[j] *= corr;
          #pragma unroll
          for (int i=0;i<8;i++) acc_o[i][j] *= corr;
        }
      }
      float p0[4], p1[4];
      #pragma unroll
      for (int j=0;j<4;j++){
        p0[j] = exp2f(x0[j] - mrow[j]);
        p1[j] = exp2f(x1[j] - mrow[j]);
        lpart[j] += p0[j] + p1[j];
      }
      #pragma unroll
      for (int j=0;j<4;j++){
        unsigned pk;
        asm("v_cvt_pk_bf16_f32 %0, %1, %2" : "=v"(pk) : "v"(p0[j]), "v"(p1[j]));
        Ps[w][(kq*4+j)*VP + fr]      = (ushort_t)(pk & 0xFFFFu);
        Ps[w][(kq*4+j)*VP + 16 + fr] = (ushort_t)(pk >> 16);
      }
      short8 ap = *(const short8*)&Ps[w][fr*VP + kq*8];
      __builtin_amdgcn_s_setprio(1);
      #pragma unroll
      for (int v8=0; v8<8; v8++){
        short8 bv = *(const short8*)&Vs[(v8*16 + fr)*VP + kq*8];
        acc_o[v8] = __builtin_amdgcn_mfma_f32_16x16x32_bf16(ap, bv, acc_o[v8], 0,0,0);
      }
      __builtin_amdgcn_s_setprio(0);
      __syncthreads();
    }

    #pragma unroll
    for (int m=1;m<16;m<<=1){
      #pragma unroll
      for (int j=0;j<4;j++) lpart[j] += __shfl_xor(lpart[j], m, 64);
    }
    #pragma unroll
    for (int v8=0; v8<8; v8++){
      #pragma unroll
      for (int j=0;j<4;j++){
        int qg = q0 + w*16 + kq*4 + j;
        float o = acc_o[v8][j] / lpart[j];
        out[(size_t)(batch*Sc + qg)*(Hc*VDc) + h*VDc + v8*16 + fr] = f2bf(o);
      }
    }
  }
}

// ---------------- launcher ----------------
extern "C" void kernel_launch(void* const* d_in, const int* in_sizes, int n_in,
                              void* d_out, int out_size, void* d_ws, size_t ws_size,
                              hipStream_t stream) {
  (void)in_sizes; (void)n_in; (void)out_size; (void)ws_size;
  const float* hidden  = (const float*)d_in[0];
  const float* q_a_w   = (const float*)d_in[3];
  const float* q_a_ln  = (const float*)d_in[4];
  const float* q_b_w   = (const float*)d_in[5];
  const float* kv_a_w  = (const float*)d_in[6];
  const float* kv_a_ln = (const float*)d_in[7];
  const float* kv_b_w  = (const float*)d_in[8];
  const float* o_w     = (const float*)d_in[9];
  float* outp = (float*)d_out;

  char* ws = (char*)d_ws;
  size_t off = 0;
  auto alloc = [&](size_t n)->char*{ char* p = ws + off; off += (n + 255) & ~(size_t)255; return p; };
  ushort_t* hbf  = (ushort_t*)alloc((size_t)Bc*Sc*HIDc*2);      // hidden bf16; later o_w bf16
  ushort_t* wqa  = (ushort_t*)alloc((size_t)QLRc*HIDc*2);       // later aliased as aout
  ushort_t* wqb  = (ushort_t*)alloc((size_t)Hc*QHDc*QLRc*2);
  ushort_t* wkva = (ushort_t*)alloc((size_t)640*HIDc*2);        // padded rows (over-read)
  ushort_t* wkvb = (ushort_t*)alloc((size_t)Hc*256*KVLRc*2);
  ushort_t* qa   = (ushort_t*)alloc((size_t)Bc*Sc*QLRc*2);
  ushort_t* qbf  = (ushort_t*)alloc((size_t)Bc*Sc*Hc*QHDc*2);
  ushort_t* ckv  = (ushort_t*)alloc((size_t)Bc*Sc*576*2);
  ushort_t* kvbf = (ushort_t*)alloc((size_t)Bc*Sc*Hc*256*2);
  ushort_t* vtb  = (ushort_t*)alloc((size_t)Bc*Hc*VDc*Sc*2);    // V transposed [bh][vd][s]
  float*    ct   = (float*)alloc((size_t)Sc*32*4);
  float*    st   = (float*)alloc((size_t)Sc*32*4);
  ushort_t* aout = wqa;   // alias: wqa+wqb+wkva (60 MB region) free before attn

  const int M = Bc*Sc; // 4096

  // one batched convert: hidden + q_a_w + q_b_w + kv_a_w + kv_b_w
  conv_all<<<2048,256,0,stream>>>(hidden, q_a_w, q_b_w, kv_a_w, kv_b_w,
                                  hbf, wqa, wqb, wkva, wkvb);
  // q_a = hidden @ q_a_w^T   [4096,1536,4096]
  gemm256x128<true><<<(M/256)*(QLRc/128),512,0,stream>>>(hbf, wqa, qa, M, QLRc, HIDc, HIDc);
  // ckv = hidden @ kv_a_w^T  (N=576 -> 128^2 kernel, bounds-checked cols)
  gemm_bt<true><<<dim3(5, M/128),256,0,stream>>>(hbf, wkva, ckv, M, KVLRc+ROPEc, HIDc, HIDc);
  // merged RMSNorm (qa + ckv)
  rmsnorm2<<<2*M,256,0,stream>>>(qa, q_a_ln, ckv, kv_a_ln);
  // hbf free now -> convert o_w into it
  f32_to_bf16<<<2048,256,0,stream>>>(o_w, hbf, (long long)HIDc*HIDc);
  // q = q_a @ q_b_w^T  [4096,6144,1536]
  gemm256x128<true><<<(M/256)*(Hc*QHDc/128),512,0,stream>>>(qa, wqb, qbf, M, Hc*QHDc, QLRc, QLRc);
  // kv = ckv_norm @ kv_b_w^T  [4096,8192,512] (coalesced C)
  gemm256<true><<<(M/256)*(Hc*256/256),512,0,stream>>>(ckv, wkvb, kvbf, M, Hc*256, KVLRc, 576);
  // RoPE
  rope_tab<<<CDIV(Sc*32,256),256,0,stream>>>(ct, st);
  rope_qk<<<CDIV(Bc*Sc*Hc*32 + Bc*Sc*32,256),256,0,stream>>>(qbf, ckv, ct, st);
  // V transpose + attention (1024 uniform blocks, diagonal-paired)
  vtrans<<<dim3(Sc/64, Bc*Hc),256,0,stream>>>(kvbf, vtb);
  attn_fwd<<<dim3(Bc*Hc, 16),256,0,stream>>>(qbf, kvbf, ckv, vtb, aout);
  // out = attn @ o_w^T  [4096,4096,4096], f32 store
  gemm256<false><<<(M/256)*(HIDc/256),512,0,stream>>>(aout, hbf, outp, M, HIDc, HIDc, HIDc);
}

// Round 9
// 666.804 us; speedup vs baseline: 1.6168x; 1.0524x over previous
//
#include <hip/hip_runtime.h>
#include <hip/hip_bf16.h>

typedef __attribute__((ext_vector_type(8))) short short8;
typedef __attribute__((ext_vector_type(4))) float f32x4;
typedef unsigned short ushort_t;

static constexpr int Bc = 2, Sc = 2048, HIDc = 4096, Hc = 32;
static constexpr int NOPEc = 128, ROPEc = 64, VDc = 128, QHDc = 192;
static constexpr int QLRc = 1536, KVLRc = 512;
static constexpr int CKVS = 640;   // padded ckv row stride (576 -> 640)

#define CDIV(a,b) (((a)+(b)-1)/(b))

__device__ __forceinline__ float bf2f(ushort_t u){
  union { unsigned u32; float f; } x; x.u32 = ((unsigned)u) << 16; return x.f;
}
__device__ __forceinline__ ushort_t f2bf(float f){
  union { float f; unsigned u32; } x; x.f = f;
  unsigned r = x.u32 + 0x7FFFu + ((x.u32 >> 16) & 1u);
  return (ushort_t)(r >> 16);
}
__device__ __forceinline__ void gload16(const void* g, void* l){
  __builtin_amdgcn_global_load_lds((const __attribute__((address_space(1))) void*)g,
                                   (__attribute__((address_space(3))) void*)l, 16, 0, 0);
}

// ---------------- f32 -> bf16 convert (vectorized, grid-stride) ----------------
__global__ __launch_bounds__(256)
void f32_to_bf16(const float* __restrict__ in, ushort_t* __restrict__ out, long long n){
  long long stride = (long long)gridDim.x * 256 * 4;
  for (long long i = ((long long)blockIdx.x*256 + threadIdx.x)*4; i < n; i += stride){
    float4 v = *(const float4*)(in + i);
    unsigned long long pk = (unsigned long long)f2bf(v.x)
                          | ((unsigned long long)f2bf(v.y) << 16)
                          | ((unsigned long long)f2bf(v.z) << 32)
                          | ((unsigned long long)f2bf(v.w) << 48);
    *(unsigned long long*)(out + i) = pk;
  }
}

// ---------------- batched 5-segment f32->bf16 (hidden + 4 weights) ----------------
__global__ __launch_bounds__(256)
void conv_all(const float* __restrict__ s0, const float* __restrict__ s1,
              const float* __restrict__ s2, const float* __restrict__ s3,
              const float* __restrict__ s4,
              ushort_t* __restrict__ d0, ushort_t* __restrict__ d1,
              ushort_t* __restrict__ d2, ushort_t* __restrict__ d3,
              ushort_t* __restrict__ d4){
  constexpr long long C0 = 16777216, C1 = 23068672, C2 = 32505856, C3 = 34865152, C4 = 39059456;
  long long stride = (long long)gridDim.x * 256 * 4;
  for (long long e = ((long long)blockIdx.x*256 + threadIdx.x)*4; e < C4; e += stride){
    const float* sp; ushort_t* dp; long long o;
    if      (e < C0){ sp = s0; dp = d0; o = e; }
    else if (e < C1){ sp = s1; dp = d1; o = e - C0; }
    else if (e < C2){ sp = s2; dp = d2; o = e - C1; }
    else if (e < C3){ sp = s3; dp = d3; o = e - C2; }
    else            { sp = s4; dp = d4; o = e - C3; }
    float4 v = *(const float4*)(sp + o);
    unsigned long long pk = (unsigned long long)f2bf(v.x)
                          | ((unsigned long long)f2bf(v.y) << 16)
                          | ((unsigned long long)f2bf(v.z) << 32)
                          | ((unsigned long long)f2bf(v.w) << 48);
    *(unsigned long long*)(dp + o) = pk;
  }
}

// ======== GEMM 256x256 tile, BK=64, 8 waves, dbuf LDS, swizzled, counted vmcnt ======
template<bool OUTBF>
__global__ __launch_bounds__(512, 2)
void gemm256(const ushort_t* __restrict__ A, const ushort_t* __restrict__ Bw,
             void* __restrict__ Cp, int M, int N, int K, int lda)
{
  __shared__ __attribute__((aligned(16))) ushort_t sm[65536];
  const int tid = threadIdx.x, lane = tid & 63, w = tid >> 6;
  const int wr = w >> 2, wc = w & 3;
  const int fr = lane & 15, kq = lane >> 4;

  const int nwg = gridDim.x, nx = N >> 8;
  const int bid = blockIdx.x;
  const int swz = (bid & 7) * (nwg >> 3) + (bid >> 3);
  const int m0 = (swz / nx) << 8, n0 = (swz % nx) << 8;

  f32x4 acc[8][4];
  #pragma unroll
  for (int m=0;m<8;m++)
    #pragma unroll
    for (int n=0;n<4;n++) acc[m][n] = (f32x4){0.f,0.f,0.f,0.f};

  const int srow = tid >> 3;
  const int gch  = (tid & 7) ^ (srow & 7);

  auto stage = [&](int c, int kt){
    const int k0 = kt << 6;
    ushort_t* Al = sm + c*16384;
    ushort_t* Bl = sm + 32768 + c*16384;
    const ushort_t* Ag = A  + (size_t)(m0 + srow)*lda + k0 + gch*8;
    const ushort_t* Bg = Bw + (size_t)(n0 + srow)*K   + k0 + gch*8;
    #pragma unroll
    for (int i=0;i<4;i++) gload16(Ag + (size_t)(i*64)*lda, Al + i*4096 + tid*8);
    #pragma unroll
    for (int i=0;i<4;i++) gload16(Bg + (size_t)(i*64)*K,   Bl + i*4096 + tid*8);
  };

  auto compute = [&](int c){
    const ushort_t* Al = sm + c*16384;
    const ushort_t* Bl = sm + 32768 + c*16384;
    const int s = fr & 7;
    short8 bfr[4][2];
    #pragma unroll
    for (int n=0;n<4;n++){
      const int row = wc*64 + n*16 + fr;
      bfr[n][0] = *(const short8*)(Bl + row*64 + ((kq    ) ^ s)*8);
      bfr[n][1] = *(const short8*)(Bl + row*64 + ((kq + 4) ^ s)*8);
    }
    #pragma unroll
    for (int m=0;m<8;m++){
      const int row = wr*128 + m*16 + fr;
      short8 a0 = *(const short8*)(Al + row*64 + ((kq    ) ^ s)*8);
      short8 a1 = *(const short8*)(Al + row*64 + ((kq + 4) ^ s)*8);
      #pragma unroll
      for (int n=0;n<4;n++){
        acc[m][n] = __builtin_amdgcn_mfma_f32_16x16x32_bf16(a0, bfr[n][0], acc[m][n], 0,0,0);
        acc[m][n] = __builtin_amdgcn_mfma_f32_16x16x32_bf16(a1, bfr[n][1], acc[m][n], 0,0,0);
      }
    }
  };

  const int nkt = K >> 6;
  stage(0, 0);
  stage(1, 1);
  asm volatile("s_waitcnt vmcnt(8)" ::: "memory");
  __builtin_amdgcn_s_barrier();
  __builtin_amdgcn_sched_barrier(0);

  int cur = 0;
  for (int kt = 0; kt < nkt; ++kt){
    compute(cur);
    __builtin_amdgcn_s_barrier();
    __builtin_amdgcn_sched_barrier(0);
    if (kt + 2 < nkt){
      stage(cur, kt + 2);
      asm volatile("s_waitcnt vmcnt(8)" ::: "memory");
    } else {
      asm volatile("s_waitcnt vmcnt(0)" ::: "memory");
    }
    __builtin_amdgcn_s_barrier();
    __builtin_amdgcn_sched_barrier(0);
    cur ^= 1;
  }

  const int rb = m0 + wr*128 + kq*4;
  const int cb = n0 + wc*64 + fr;
  #pragma unroll
  for (int m=0;m<8;m++)
    #pragma unroll
    for (int n=0;n<4;n++){
      const int col = cb + n*16;
      #pragma unroll
      for (int j=0;j<4;j++){
        const int row = rb + m*16 + j;
        float v = acc[m][n][j];
        if (OUTBF) ((ushort_t*)Cp)[(size_t)row*N + col] = f2bf(v);
        else       ((float*)  Cp)[(size_t)row*N + col] = v;
      }
    }
}

// ======== GEMM 256x128 tile, BK=64, 8 waves (4Mx2N), dbuf, counted vmcnt ======
template<bool OUTBF>
__global__ __launch_bounds__(512, 2)
void gemm256x128(const ushort_t* __restrict__ A, const ushort_t* __restrict__ Bw,
                 void* __restrict__ Cp, int M, int N, int K, int lda)
{
  __shared__ __attribute__((aligned(16))) ushort_t sm[49152];
  const int tid = threadIdx.x, lane = tid & 63, w = tid >> 6;
  const int wr = w >> 1, wc = w & 1;
  const int fr = lane & 15, kq = lane >> 4;

  const int nwg = gridDim.x, nx = N >> 7;
  const int bid = blockIdx.x;
  const int swz = (bid & 7) * (nwg >> 3) + (bid >> 3);
  const int m0 = (swz / nx) << 8, n0 = (swz % nx) << 7;

  f32x4 acc[4][4];
  #pragma unroll
  for (int m=0;m<4;m++)
    #pragma unroll
    for (int n=0;n<4;n++) acc[m][n] = (f32x4){0.f,0.f,0.f,0.f};

  const int srow = tid >> 3;
  const int gch  = (tid & 7) ^ (srow & 7);

  auto stage = [&](int c, int kt){
    const int k0 = kt << 6;
    ushort_t* Al = sm + c*16384;
    ushort_t* Bl = sm + 32768 + c*8192;
    const ushort_t* Ag = A  + (size_t)(m0 + srow)*lda + k0 + gch*8;
    const ushort_t* Bg = Bw + (size_t)(n0 + srow)*K   + k0 + gch*8;
    #pragma unroll
    for (int i=0;i<4;i++) gload16(Ag + (size_t)(i*64)*lda, Al + i*4096 + tid*8);
    #pragma unroll
    for (int i=0;i<2;i++) gload16(Bg + (size_t)(i*64)*K,   Bl + i*4096 + tid*8);
  };

  auto compute = [&](int c){
    const ushort_t* Al = sm + c*16384;
    const ushort_t* Bl = sm + 32768 + c*8192;
    const int s = fr & 7;
    short8 bfr[4][2];
    #pragma unroll
    for (int n=0;n<4;n++){
      const int row = wc*64 + n*16 + fr;
      bfr[n][0] = *(const short8*)(Bl + row*64 + ((kq    ) ^ s)*8);
      bfr[n][1] = *(const short8*)(Bl + row*64 + ((kq + 4) ^ s)*8);
    }
    #pragma unroll
    for (int m=0;m<4;m++){
      const int row = wr*64 + m*16 + fr;
      short8 a0 = *(const short8*)(Al + row*64 + ((kq    ) ^ s)*8);
      short8 a1 = *(const short8*)(Al + row*64 + ((kq + 4) ^ s)*8);
      #pragma unroll
      for (int n=0;n<4;n++){
        acc[m][n] = __builtin_amdgcn_mfma_f32_16x16x32_bf16(a0, bfr[n][0], acc[m][n], 0,0,0);
        acc[m][n] = __builtin_amdgcn_mfma_f32_16x16x32_bf16(a1, bfr[n][1], acc[m][n], 0,0,0);
      }
    }
  };

  const int nkt = K >> 6;
  stage(0, 0);
  stage(1, 1);
  asm volatile("s_waitcnt vmcnt(6)" ::: "memory");
  __builtin_amdgcn_s_barrier();
  __builtin_amdgcn_sched_barrier(0);

  int cur = 0;
  for (int kt = 0; kt < nkt; ++kt){
    compute(cur);
    __builtin_amdgcn_s_barrier();
    __builtin_amdgcn_sched_barrier(0);
    if (kt + 2 < nkt){
      stage(cur, kt + 2);
      asm volatile("s_waitcnt vmcnt(6)" ::: "memory");
    } else {
      asm volatile("s_waitcnt vmcnt(0)" ::: "memory");
    }
    __builtin_amdgcn_s_barrier();
    __builtin_amdgcn_sched_barrier(0);
    cur ^= 1;
  }

  const int rb = m0 + wr*64 + kq*4;
  const int cb = n0 + wc*64 + fr;
  #pragma unroll
  for (int m=0;m<4;m++)
    #pragma unroll
    for (int n=0;n<4;n++){
      const int col = cb + n*16;
      #pragma unroll
      for (int j=0;j<4;j++){
        const int row = rb + m*16 + j;
        float v = acc[m][n][j];
        if (OUTBF) ((ushort_t*)Cp)[(size_t)row*N + col] = f2bf(v);
        else       ((float*)  Cp)[(size_t)row*N + col] = v;
      }
    }
}

// ---------------- merged RMSNorm (qa rows then ckv rows) ----------------
__global__ __launch_bounds__(256)
void rmsnorm2(ushort_t* __restrict__ xa, const float* __restrict__ wa,
              ushort_t* __restrict__ xb, const float* __restrict__ wb){
  const int row = blockIdx.x;
  ushort_t* p; const float* w; int D;
  if (row < Bc*Sc){ p = xa + (size_t)row*QLRc; w = wa; D = QLRc; }
  else            { p = xb + (size_t)(row - Bc*Sc)*CKVS; w = wb; D = KVLRc; }
  float ss = 0.f;
  for (int c = threadIdx.x*8; c < D; c += 2048) {
    short8 v = *(const short8*)(p + c);
    #pragma unroll
    for (int j=0;j<8;j++){ float f = bf2f((ushort_t)v[j]); ss += f*f; }
  }
  #pragma unroll
  for (int m=1;m<64;m<<=1) ss += __shfl_xor(ss, m, 64);
  __shared__ float red[4];
  if ((threadIdx.x & 63)==0) red[threadIdx.x>>6] = ss;
  __syncthreads();
  float tot = red[0]+red[1]+red[2]+red[3];
  float inv = rsqrtf(tot/(float)D + 1e-6f);
  for (int c = threadIdx.x*8; c < D; c += 2048) {
    short8 v = *(const short8*)(p + c);
    short8 o;
    #pragma unroll
    for (int j=0;j<8;j++) o[j] = (short)f2bf(bf2f((ushort_t)v[j]) * inv * w[c+j]);
    *(short8*)(p + c) = o;
  }
}

// ---------------- RoPE tables ----------------
__global__ void rope_tab(float* __restrict__ ct, float* __restrict__ st){
  int i = blockIdx.x*256 + threadIdx.x;
  if (i >= Sc*32) return;
  int t = i >> 5, p = i & 31;
  float invf = exp2f(-(float)p * (13.287712379549449f / 32.f));
  float ang = (float)t * invf;
  ct[i] = cosf(ang);
  st[i] = sinf(ang);
}

// ---------------- merged RoPE for q and k ----------------
__global__ void rope_qk(ushort_t* __restrict__ q, ushort_t* __restrict__ ckv,
                        const float* __restrict__ ct, const float* __restrict__ st){
  const int NQ = Bc*Sc*Hc*32;
  int i = blockIdx.x*256 + threadIdx.x;
  if (i < NQ) {
    int p = i & 31, h = (i >> 5) & (Hc-1);
    int bs = i >> 10;
    int t = bs & (Sc-1);
    ushort_t* base = q + (size_t)bs*Hc*QHDc + h*QHDc + NOPEc + 2*p;
    unsigned u = *(const unsigned*)base;
    float a = bf2f((ushort_t)(u & 0xFFFFu)), bb = bf2f((ushort_t)(u >> 16));
    float c = ct[t*32+p], s = st[t*32+p];
    unsigned o = (unsigned)f2bf(a*c - bb*s) | ((unsigned)f2bf(bb*c + a*s) << 16);
    *(unsigned*)base = o;
  } else {
    int k = i - NQ;
    if (k >= Bc*Sc*32) return;
    int p = k & 31;
    int bs = k >> 5;
    int t = bs & (Sc-1);
    ushort_t* base = ckv + (size_t)bs*CKVS + 512 + 2*p;
    unsigned u = *(const unsigned*)base;
    float a = bf2f((ushort_t)(u & 0xFFFFu)), bb = bf2f((ushort_t)(u >> 16));
    float c = ct[t*32+p], s = st[t*32+p];
    unsigned o = (unsigned)f2bf(a*c - bb*s) | ((unsigned)f2bf(bb*c + a*s) << 16);
    *(unsigned*)base = o;
  }
}

// ---------------- V transpose: kv[bs][h][256](+128) -> vt[bh][vd][s] ----------------
__global__ __launch_bounds__(256)
void vtrans(const ushort_t* __restrict__ kv, ushort_t* __restrict__ vt){
  const int s0 = blockIdx.x * 64;
  const int bh = blockIdx.y;
  const int batch = bh >> 5, h = bh & 31;
  __shared__ __attribute__((aligned(16))) ushort_t L[64][136];
  #pragma unroll
  for (int i = 0; i < 4; i++) {
    int chunk = i*256 + threadIdx.x;
    int r = chunk >> 4;
    int c = (chunk & 15) * 8;
    short8 v = *(const short8*)(kv + ((size_t)(batch*Sc + s0 + r)*Hc + h)*256 + 128 + c);
    *(short8*)&L[r][c] = v;
  }
  __syncthreads();
  #pragma unroll
  for (int i = 0; i < 4; i++) {
    int chunk = i*256 + threadIdx.x;
    int vd = chunk >> 3;
    int sc2 = (chunk & 7) * 8;
    short8 o;
    #pragma unroll
    for (int j=0;j<8;j++) o[j] = (short)L[sc2+j][vd];
    *(short8*)(vt + ((size_t)bh*VDc + vd)*Sc + s0 + sc2) = o;
  }
}

// ---------------- Flash attention (causal), 4 waves, 2-deep prefetch ----------------
// Diagonal pairing: block (bh, y) processes q-tiles {31-y, y} sequentially ->
// every block does exactly 66 KV-tile iterations; same-bh blocks stream K/V in
// lockstep -> L2/L3 reuse (FETCH ~110MB). Prefetch depth 2 (named reg sets A/B,
// ktiles is always even) doubles the latency budget for the reg-staged loads.
__global__ __launch_bounds__(256)
void attn_fwd(const ushort_t* __restrict__ qb, const ushort_t* __restrict__ kvb,
              const ushort_t* __restrict__ ckv, const ushort_t* __restrict__ vt,
              ushort_t* __restrict__ out)
{
  constexpr int KP = 200, VP = 40;   // padded strides: 2-way-bank-conflict only
  __shared__ __attribute__((aligned(16))) ushort_t Ks[32*KP];
  __shared__ __attribute__((aligned(16))) ushort_t Vs[128*VP];
  __shared__ __attribute__((aligned(16))) ushort_t Ps[4][16*VP];
  const int tid = threadIdx.x, lane = tid & 63, w = tid >> 6;
  const int fr = lane & 15, kq = lane >> 4;
  const int y = (int)blockIdx.y;                      // 0..15
  const int bh = blockIdx.x, batch = bh >> 5, h = bh & 31;

  const float scl = 0.07216878364870323f * 1.4426950408889634f; // 192^-0.5 * log2(e)
  const float THR = 8.0f;

  const int ksr = tid >> 3, ksub = tid & 7;   // K staging: 32 rows x 24 chunks
  const int vvd = tid >> 1, vsub = tid & 1;   // V staging: 128 rows x 4 chunks

  const ushort_t* kbase  = kvb + ((size_t)batch*Sc + ksr)*((size_t)Hc*256) + (size_t)h*256;
  const ushort_t* pebase = ckv + (size_t)(batch*Sc + ksr)*CKVS + 512;
  const ushort_t* vbase  = vt + ((size_t)bh*VDc + vvd)*Sc;

  constexpr size_t KST2  = (size_t)64*Hc*256;   // 2 KV-tiles of K rows
  constexpr size_t PEST2 = (size_t)64*CKVS;
  constexpr size_t VST2  = 64;
  constexpr size_t KST1  = (size_t)32*Hc*256;   // 1 KV-tile
  constexpr size_t PEST1 = (size_t)32*CKVS;
  constexpr size_t VST1  = 32;

  for (int seg = 0; seg < 2; ++seg) {
    const int qt = seg == 0 ? (31 - y) : y;           // heavy tile first
    const int q0 = qt * 64;

    const int qrow = q0 + w*16 + fr;
    const ushort_t* qptr = qb + ((size_t)(batch*Sc + qrow)*Hc + h)*QHDc;
    short8 qf[6];
    #pragma unroll
    for (int kk=0;kk<6;kk++) qf[kk] = *(const short8*)(qptr + kk*32 + kq*8);

    f32x4 acc_o[8];
    #pragma unroll
    for (int i=0;i<8;i++) acc_o[i] = (f32x4){0.f,0.f,0.f,0.f};
    float mrow[4]  = {-3e38f,-3e38f,-3e38f,-3e38f};
    float lpart[4] = {0.f,0.f,0.f,0.f};

    const int ktiles = q0/32 + 2;                     // = 2*qt+2 -> always EVEN

    // two named prefetch register sets (static indexing only — rule #20)
    short8 krA[3], vrA[2], krB[3], vrB[2];
    const ushort_t *kpA = kbase,        *peA = pebase,         *vpA = vbase;
    const ushort_t *kpB = kbase + KST1, *peB = pebase + PEST1, *vpB = vbase + VST1;

    auto loadSet = [&](short8 (&kr)[3], short8 (&vr)[2],
                       const ushort_t* kp, const ushort_t* pe, const ushort_t* vp){
      #pragma unroll
      for (int i=0;i<3;i++){
        int c = (ksub*3 + i)*8;
        kr[i] = (c < 128) ? *(const short8*)(kp + c)
                          : *(const short8*)(pe + (c - 128));
      }
      #pragma unroll
      for (int i=0;i<2;i++) vr[i] = *(const short8*)(vp + (vsub*2+i)*8);
    };

    auto body = [&](int kt, short8 (&kr)[3], short8 (&vr)[2], bool reload,
                    const ushort_t* kp, const ushort_t* pe, const ushort_t* vp){
      const int j0 = kt*32;
      // publish the staged tile (loaded 2 iterations ago)
      #pragma unroll
      for (int i=0;i<3;i++) *(short8*)&Ks[ksr*KP + (ksub*3 + i)*8] = kr[i];
      #pragma unroll
      for (int i=0;i<2;i++) *(short8*)&Vs[vvd*VP + (vsub*2 + i)*8] = vr[i];
      __syncthreads();

      if (reload) loadSet(kr, vr, kp, pe, vp);   // tile kt+2, lands by iter kt+2

      f32x4 s0 = (f32x4){0.f,0.f,0.f,0.f}, s1 = (f32x4){0.f,0.f,0.f,0.f};
      __builtin_amdgcn_s_setprio(1);
      #pragma unroll
      for (int kk=0;kk<6;kk++){
        short8 b0 = *(const short8*)&Ks[fr*KP + kk*32 + kq*8];
        short8 b1 = *(const short8*)&Ks[(16+fr)*KP + kk*32 + kq*8];
        s0 = __builtin_amdgcn_mfma_f32_16x16x32_bf16(qf[kk], b0, s0, 0,0,0);
        s1 = __builtin_amdgcn_mfma_f32_16x16x32_bf16(qf[kk], b1, s1, 0,0,0);
      }
      __builtin_amdgcn_s_setprio(0);

      const bool full = (j0 + 31 <= q0 + w*16);
      float x0[4], x1[4];
      int okl = 1;
      #pragma unroll
      for (int j=0;j<4;j++){
        float a  = s0[j]*scl, c2 = s1[j]*scl;
        if (!full) {
          int qp = q0 + w*16 + kq*4 + j;
          if (j0 + fr      > qp) a  = -3e38f;
          if (j0 + 16 + fr > qp) c2 = -3e38f;
        }
        x0[j] = a; x1[j] = c2;
        okl &= (fmaxf(a, c2) <= mrow[j] + THR) ? 1 : 0;
      }
      if (!__all(okl)) {
        float tmax[4];
        #pragma unroll
        for (int j=0;j<4;j++) tmax[j] = fmaxf(x0[j], x1[j]);
        #pragma unroll
        for (int m=1;m<16;m<<=1){
          #pragma unroll
          for (int j=0;j<4;j++) tmax[j] = fmaxf(tmax[j], __shfl_xor(tmax[j], m, 64));
        }
        #pragma unroll
        for (int j=0;j<4;j++){
          float mn = fmaxf(mrow[j], tmax[j]);
          float corr = exp2f(mrow[j] - mn);
          mrow[j] = mn;
          lpart[j] *= corr;
          #pragma unroll
          for (int i=0;i<8;i++) acc_o[i][j] *= corr;
        }
      }
      float p0[4], p1[4];
      #pragma unroll
      for (int j=0;j<4;j++){
        p0[j] = exp2f(x0[j] - mrow[j]);
        p1[j] = exp2f(x1[j] - mrow[j]);
        lpart[j] += p0[j] + p1[j];
      }
      #pragma unroll
      for (int j=0;j<4;j++){
        unsigned pk;
        asm("v_cvt_pk_bf16_f32 %0, %1, %2" : "=v"(pk) : "v"(p0[j]), "v"(p1[j]));
        Ps[w][(kq*4+j)*VP + fr]      = (ushort_t)(pk & 0xFFFFu);
        Ps[w][(kq*4+j)*VP + 16 + fr] = (ushort_t)(pk >> 16);
      }
      short8 ap = *(const short8*)&Ps[w][fr*VP + kq*8];
      __builtin_amdgcn_s_setprio(1);
      #pragma unroll
      for (int v8=0; v8<8; v8++){
        short8 bv = *(const short8*)&Vs[(v8*16 + fr)*VP + kq*8];
        acc_o[v8] = __builtin_amdgcn_mfma_f32_16x16x32_bf16(ap, bv, acc_o[v8], 0,0,0);
      }
      __builtin_amdgcn_s_setprio(0);
      __syncthreads();
    };

    // prologue: fill both sets (tiles 0 and 1); advance to tiles 2 and 3
    loadSet(krA, vrA, kpA, peA, vpA); kpA += KST2; peA += PEST2; vpA += VST2;
    loadSet(krB, vrB, kpB, peB, vpB); kpB += KST2; peB += PEST2; vpB += VST2;

    for (int kt = 0; kt < ktiles; kt += 2){
      body(kt,   krA, vrA, (kt + 2 < ktiles), kpA, peA, vpA);
      kpA += KST2; peA += PEST2; vpA += VST2;
      body(kt+1, krB, vrB, (kt + 3 < ktiles), kpB, peB, vpB);
      kpB += KST2; peB += PEST2; vpB += VST2;
    }

    #pragma unroll
    for (int m=1;m<16;m<<=1){
      #pragma unroll
      for (int j=0;j<4;j++) lpart[j] += __shfl_xor(lpart[j], m, 64);
    }
    #pragma unroll
    for (int v8=0; v8<8; v8++){
      #pragma unroll
      for (int j=0;j<4;j++){
        int qg = q0 + w*16 + kq*4 + j;
        float o = acc_o[v8][j] / lpart[j];
        out[(size_t)(batch*Sc + qg)*(Hc*VDc) + h*VDc + v8*16 + fr] = f2bf(o);
      }
    }
  }
}

// ---------------- launcher ----------------
extern "C" void kernel_launch(void* const* d_in, const int* in_sizes, int n_in,
                              void* d_out, int out_size, void* d_ws, size_t ws_size,
                              hipStream_t stream) {
  (void)in_sizes; (void)n_in; (void)out_size; (void)ws_size;
  const float* hidden  = (const float*)d_in[0];
  const float* q_a_w   = (const float*)d_in[3];
  const float* q_a_ln  = (const float*)d_in[4];
  const float* q_b_w   = (const float*)d_in[5];
  const float* kv_a_w  = (const float*)d_in[6];
  const float* kv_a_ln = (const float*)d_in[7];
  const float* kv_b_w  = (const float*)d_in[8];
  const float* o_w     = (const float*)d_in[9];
  float* outp = (float*)d_out;

  char* ws = (char*)d_ws;
  size_t off = 0;
  auto alloc = [&](size_t n)->char*{ char* p = ws + off; off += (n + 255) & ~(size_t)255; return p; };
  ushort_t* hbf  = (ushort_t*)alloc((size_t)Bc*Sc*HIDc*2);      // hidden bf16; later o_w bf16
  ushort_t* wqa  = (ushort_t*)alloc((size_t)QLRc*HIDc*2);       // later aliased as aout
  ushort_t* wqb  = (ushort_t*)alloc((size_t)Hc*QHDc*QLRc*2);
  ushort_t* wkva = (ushort_t*)alloc((size_t)640*HIDc*2);        // 640 rows (576 data + pad)
  ushort_t* wkvb = (ushort_t*)alloc((size_t)Hc*256*KVLRc*2);
  ushort_t* qa   = (ushort_t*)alloc((size_t)Bc*Sc*QLRc*2);
  ushort_t* qbf  = (ushort_t*)alloc((size_t)Bc*Sc*Hc*QHDc*2);
  ushort_t* ckv  = (ushort_t*)alloc((size_t)Bc*Sc*CKVS*2);      // stride 640
  ushort_t* kvbf = (ushort_t*)alloc((size_t)Bc*Sc*Hc*256*2);
  ushort_t* vtb  = (ushort_t*)alloc((size_t)Bc*Hc*VDc*Sc*2);    // V transposed [bh][vd][s]
  float*    ct   = (float*)alloc((size_t)Sc*32*4);
  float*    st   = (float*)alloc((size_t)Sc*32*4);
  ushort_t* aout = wqa;   // alias: wqa+wqb+wkva free before attn

  const int M = Bc*Sc; // 4096

  // one batched convert: hidden + q_a_w + q_b_w + kv_a_w + kv_b_w
  conv_all<<<2048,256,0,stream>>>(hidden, q_a_w, q_b_w, kv_a_w, kv_b_w,
                                  hbf, wqa, wqb, wkva, wkvb);
  // q_a = hidden @ q_a_w^T   [4096,1536,4096]
  gemm256x128<true><<<(M/256)*(QLRc/128),512,0,stream>>>(hbf, wqa, qa, M, QLRc, HIDc, HIDc);
  // ckv = hidden @ kv_a_w^T  (N padded to 640; cols 576..639 are garbage, never read)
  gemm256x128<true><<<(M/256)*(640/128),512,0,stream>>>(hbf, wkva, ckv, M, CKVS, HIDc, HIDc);
  // merged RMSNorm (qa + ckv)
  rmsnorm2<<<2*M,256,0,stream>>>(qa, q_a_ln, ckv, kv_a_ln);
  // hbf free now -> convert o_w into it
  f32_to_bf16<<<2048,256,0,stream>>>(o_w, hbf, (long long)HIDc*HIDc);
  // q = q_a @ q_b_w^T  [4096,6144,1536]
  gemm256x128<true><<<(M/256)*(Hc*QHDc/128),512,0,stream>>>(qa, wqb, qbf, M, Hc*QHDc, QLRc, QLRc);
  // kv = ckv_norm @ kv_b_w^T  [4096,8192,512], lda=640
  gemm256<true><<<(M/256)*(Hc*256/256),512,0,stream>>>(ckv, wkvb, kvbf, M, Hc*256, KVLRc, CKVS);
  // RoPE
  rope_tab<<<CDIV(Sc*32,256),256,0,stream>>>(ct, st);
  rope_qk<<<CDIV(Bc*Sc*Hc*32 + Bc*Sc*32,256),256,0,stream>>>(qbf, ckv, ct, st);
  // V transpose + attention (1024 uniform blocks, diagonal-paired)
  vtrans<<<dim3(Sc/64, Bc*Hc),256,0,stream>>>(kvbf, vtb);
  attn_fwd<<<dim3(Bc*Hc, 16),256,0,stream>>>(qbf, kvbf, ckv, vtb, aout);
  // out = attn @ o_w^T  [4096,4096,4096], f32 store
  gemm256<false><<<(M/256)*(HIDc/256),512,0,stream>>>(aout, hbf, outp, M, HIDc, HIDc, HIDc);
}